// Round 12
// baseline (1343.372 us; speedup 1.0000x reference)
//
#include <hip/hip_runtime.h>
#include <math.h>
#include <stdint.h>

#define NN 16384
#define DD 256
#define ETH 0.3f
#define EDGE_CAP (4*1024*1024)

typedef unsigned long long u64;
typedef uint32_t u32;
typedef float f32x4 __attribute__((ext_vector_type(4)));

// ---------- per-node stats: inverse L2 norm, salience = sigmoid(nv)*recency ----------
__global__ __launch_bounds__(256) void node_stats_k(const float* __restrict__ nodes,
    const float* __restrict__ nv, const int* __restrict__ ts, const int* __restrict__ tw,
    float* __restrict__ inv_norm, float* __restrict__ sal){
  int row = blockIdx.x*4 + (threadIdx.x>>6);
  int lane = threadIdx.x & 63;
  const float4* r4 = (const float4*)(nodes + (size_t)row*DD);
  float4 v = r4[lane];
  float s = v.x*v.x+v.y*v.y+v.z*v.z+v.w*v.w;
  #pragma unroll
  for (int o=32;o>0;o>>=1) s += __shfl_down(s,o);
  if (lane==0){
    inv_norm[row] = 1.0f/(sqrtf(s)+1e-8f);
    float x = nv[row];
    float sig = 1.0f/(1.0f+expf(-x));
    float rec = expf(-0.01f*(float)(tw[0]-ts[row]));
    sal[row] = sig*rec;
  }
}

// ---------- normalize related_pos (rows 0..63) and query (rows 64..127) into qr ----------
__global__ __launch_bounds__(64) void norm_qr_k(const float* __restrict__ query,
    const float* __restrict__ related, float* __restrict__ qr){
  int blk = blockIdx.x; int lane = threadIdx.x;
  const float* src = (blk<64)? (related + (size_t)blk*DD) : (query + (size_t)(blk-64)*DD);
  float4 v = ((const float4*)src)[lane];
  float s = v.x*v.x+v.y*v.y+v.z*v.z+v.w*v.w;
  #pragma unroll
  for (int o=32;o>0;o>>=1) s += __shfl_down(s,o);
  s = __shfl(s,0);
  float inv = 1.0f/(sqrtf(s)+1e-8f);
  ((float4*)(qr + (size_t)blk*DD))[lane] = make_float4(v.x*inv,v.y*inv,v.z*inv,v.w*inv);
}

// ---------- small-M GEMM vs nodes^T ----------
#define ACC8(r) do{ \
    accA[r].x += qs*nv0.x; accA[r].y += qs*nv0.y; accA[r].z += qs*nv0.z; accA[r].w += qs*nv0.w; \
    accB[r].x += qs*nv1.x; accB[r].y += qs*nv1.y; accB[r].z += qs*nv1.z; accB[r].w += qs*nv1.w; }while(0)

template<int RM>
__global__ __launch_bounds__(256) void gemm_smallM_k(const float* __restrict__ Qm,
    const float* __restrict__ nodes, float* __restrict__ out0, float* __restrict__ out1,
    const float* __restrict__ inv_norm, const float* __restrict__ sal, int mode){
  constexpr int M = RM*32;
  constexpr int KC = 32;
  __shared__ float qk[KC*M];
  __shared__ float ndk[KC*64];
  int t = threadIdx.x;
  int qg = t>>3, ng = t&7;
  int n0 = blockIdx.x*64;
  float4 accA[RM], accB[RM];
  #pragma unroll
  for (int r=0;r<RM;r++){ accA[r]=make_float4(0,0,0,0); accB[r]=make_float4(0,0,0,0); }
  for (int kb=0; kb<DD; kb+=KC){
    if (t < M){
      const float4* src = (const float4*)(Qm + (size_t)t*DD + kb);
      #pragma unroll
      for (int i=0;i<KC/4;i++){
        float4 w = src[i];
        qk[(i*4+0)*M+t]=w.x; qk[(i*4+1)*M+t]=w.y;
        qk[(i*4+2)*M+t]=w.z; qk[(i*4+3)*M+t]=w.w;
      }
    }
    {
      int nn = t&63, kq = t>>6;
      const float4* src = (const float4*)(nodes + (size_t)(n0+nn)*DD + kb + kq*8);
      float4 a = src[0], b = src[1];
      ndk[(kq*8+0)*64+nn]=a.x; ndk[(kq*8+1)*64+nn]=a.y; ndk[(kq*8+2)*64+nn]=a.z; ndk[(kq*8+3)*64+nn]=a.w;
      ndk[(kq*8+4)*64+nn]=b.x; ndk[(kq*8+5)*64+nn]=b.y; ndk[(kq*8+6)*64+nn]=b.z; ndk[(kq*8+7)*64+nn]=b.w;
    }
    __syncthreads();
    for (int k=0;k<KC;k++){
      float4 nv0 = *(const float4*)&ndk[k*64 + ng*8];
      float4 nv1 = *(const float4*)&ndk[k*64 + ng*8 + 4];
      float4 q0  = *(const float4*)&qk[k*M + qg*RM];
      float qs;
      qs=q0.x; ACC8(0); qs=q0.y; ACC8(1); qs=q0.z; ACC8(2); qs=q0.w; ACC8(3);
      if constexpr (RM==8){
        float4 q1 = *(const float4*)&qk[k*M + qg*RM + 4];
        qs=q1.x; ACC8(4); qs=q1.y; ACC8(5); qs=q1.z; ACC8(6); qs=q1.w; ACC8(7);
      }
    }
    __syncthreads();
  }
  int nbase = n0 + ng*8;
  float4 in0, in1, sa0, sa1;
  if (mode==0){
    in0 = *(const float4*)&inv_norm[nbase]; in1 = *(const float4*)&inv_norm[nbase+4];
    sa0 = *(const float4*)&sal[nbase];      sa1 = *(const float4*)&sal[nbase+4];
  }
  #pragma unroll
  for (int r=0;r<RM;r++){
    int row = qg*RM + r;
    float4 a = accA[r], b = accB[r];
    if (mode==0){
      float4 s0 = make_float4(a.x*in0.x, a.y*in0.y, a.z*in0.z, a.w*in0.w);
      float4 s1 = make_float4(b.x*in1.x, b.y*in1.y, b.z*in1.z, b.w*in1.w);
      if (row < 64){
        *(float4*)&out0[(size_t)row*NN + nbase]     = s0;
        *(float4*)&out0[(size_t)row*NN + nbase + 4] = s1;
      } else {
        float4 w0 = make_float4(s0.x*sa0.x, s0.y*sa0.y, s0.z*sa0.z, s0.w*sa0.w);
        float4 w1 = make_float4(s1.x*sa1.x, s1.y*sa1.y, s1.z*sa1.z, s1.w*sa1.w);
        *(float4*)&out1[(size_t)(row-64)*NN + nbase]     = w0;
        *(float4*)&out1[(size_t)(row-64)*NN + nbase + 4] = w1;
      }
    } else {
      float4 s0 = make_float4(a.x*0.125f, a.y*0.125f, a.z*0.125f, a.w*0.125f);
      float4 s1 = make_float4(b.x*0.125f, b.y*0.125f, b.z*0.125f, b.w*0.125f);
      *(float4*)&out0[(size_t)row*NN + nbase]     = s0;
      *(float4*)&out0[(size_t)row*NN + nbase + 4] = s1;
    }
  }
}

// ---------- single-pass top-K: register top-5 + LDS tree merge (JAX tie-break) ----------
#define TK_INS(cv,ci) do{ \
  if (cv>v4 || (cv==v4 && ci<i4)){ \
    if (cv>v0 || (cv==v0 && ci<i0)){ v4=v3;i4=i3; v3=v2;i3=i2; v2=v1;i2=i1; v1=v0;i1=i0; v0=cv;i0=ci; } \
    else if (cv>v1 || (cv==v1 && ci<i1)){ v4=v3;i4=i3; v3=v2;i3=i2; v2=v1;i2=i1; v1=cv;i1=ci; } \
    else if (cv>v2 || (cv==v2 && ci<i2)){ v4=v3;i4=i3; v3=v2;i3=i2; v2=cv;i2=ci; } \
    else if (cv>v3 || (cv==v3 && ci<i3)){ v4=v3;i4=i3; v3=cv;i3=ci; } \
    else { v4=cv;i4=ci; } \
  } \
}while(0)

__global__ __launch_bounds__(1024) void topk_k(const float* __restrict__ src, int K,
    int* __restrict__ outIdx, u64* __restrict__ vis){
  int b = blockIdx.x, t = threadIdx.x;
  const float* row = src + (size_t)b*NN;
  float v0=-3.0e38f,v1=-3.0e38f,v2=-3.0e38f,v3=-3.0e38f,v4=-3.0e38f;
  int i0=0x7fffffff,i1=0x7fffffff,i2=0x7fffffff,i3=0x7fffffff,i4=0x7fffffff;
  for (int n=t; n<NN; n+=1024){
    float cv = row[n];
    TK_INS(cv, n);
  }
  __shared__ float sv[1024*5];
  __shared__ int   si[1024*5];
  sv[t*5+0]=v0; si[t*5+0]=i0; sv[t*5+1]=v1; si[t*5+1]=i1;
  sv[t*5+2]=v2; si[t*5+2]=i2; sv[t*5+3]=v3; si[t*5+3]=i3;
  sv[t*5+4]=v4; si[t*5+4]=i4;
  __syncthreads();
  for (int s=512; s>0; s>>=1){
    if (t < s){
      #pragma unroll
      for (int k=0;k<5;k++){
        float cv = sv[(t+s)*5+k]; int ci = si[(t+s)*5+k];
        TK_INS(cv, ci);
      }
      sv[t*5+0]=v0; si[t*5+0]=i0; sv[t*5+1]=v1; si[t*5+1]=i1;
      sv[t*5+2]=v2; si[t*5+2]=i2; sv[t*5+3]=v3; si[t*5+3]=i3;
      sv[t*5+4]=v4; si[t*5+4]=i4;
    }
    __syncthreads();
  }
  if (t==0){
    int idxs[5] = {i0,i1,i2,i3,i4};
    for (int kk=0; kk<K; kk++){
      outIdx[b*K+kk] = idxs[kk];
      if (vis) atomicOr(&vis[idxs[kk]], 1ull<<b);
    }
  }
}

// ---------- relation MLP -> edge patches ----------
__global__ __launch_bounds__(256) void rel_patch_k(const float* __restrict__ nodes,
    const int* __restrict__ write_idx, const int* __restrict__ nbr,
    const float* __restrict__ w1, const float* __restrict__ b1,
    const float* __restrict__ w2, const float* __restrict__ b2,
    const float* __restrict__ w3, const float* __restrict__ b3,
    u32* __restrict__ modkeys, u32* __restrict__ addkeys, int* __restrict__ ctrl,
    u32* __restrict__ rowmod){
  int b = blockIdx.x, t = threadIdx.x;
  __shared__ float comb[512], h1[256], red[128];
  int w = write_idx[b];
  for (int k=0;k<3;k++){
    int nb = nbr[b*3+k];
    comb[t]     = nodes[(size_t)w*DD + t];
    comb[256+t] = nodes[(size_t)nb*DD + t];
    __syncthreads();
    float a1 = b1[t];
    for (int i=0;i<512;i++) a1 += comb[i]*w1[(size_t)i*256 + t];
    h1[t] = a1>0.f ? a1 : 0.f;
    __syncthreads();
    if (t<128){
      float a2 = b2[t];
      for (int i=0;i<256;i++) a2 += h1[i]*w2[(size_t)i*128 + t];
      float h2 = a2>0.f ? a2 : 0.f;
      red[t] = h2*w3[t];
    }
    __syncthreads();
    for (int s=64;s>0;s>>=1){ if (t<s) red[t]+=red[t+s]; __syncthreads(); }
    if (t==0 && nb != w){
      float strength = 1.0f/(1.0f+expf(-(red[0]+b3[0])));
      u32 k1 = ((u32)w<<14)|(u32)nb, k2 = ((u32)nb<<14)|(u32)w;
      int m = atomicAdd(&ctrl[1],2);
      modkeys[m]=k1; modkeys[m+1]=k2;
      if (strength > ETH){ int a=atomicAdd(&ctrl[2],2); addkeys[a]=k1; addkeys[a+1]=k2; }
      atomicOr(&rowmod[(u32)w>>5], 1u<<((u32)w&31));
      atomicOr(&rowmod[(u32)nb>>5], 1u<<((u32)nb&31));
    }
    __syncthreads();
  }
}

// ---------- 1 GB adjacency scan -> edge list + FUSED HOP-1 (V1 |= V0[i] per edge).
// r9 counted-vmcnt structure + nt (non-temporal) loads: 1 GB stream has zero
// reuse; nt bypasses LLC alloc-on-miss. ----------
#define LCAP 4096
#define GITER 8
#define ISSUE(P, GB) do{ \
  asm volatile("global_load_dwordx4 %0, %1, off nt" : "=v"(P##0) : "v"(a4 + tid + (size_t)((GB)+0)*stride)); \
  asm volatile("global_load_dwordx4 %0, %1, off nt" : "=v"(P##1) : "v"(a4 + tid + (size_t)((GB)+1)*stride)); \
  asm volatile("global_load_dwordx4 %0, %1, off nt" : "=v"(P##2) : "v"(a4 + tid + (size_t)((GB)+2)*stride)); \
  asm volatile("global_load_dwordx4 %0, %1, off nt" : "=v"(P##3) : "v"(a4 + tid + (size_t)((GB)+3)*stride)); \
  asm volatile("global_load_dwordx4 %0, %1, off nt" : "=v"(P##4) : "v"(a4 + tid + (size_t)((GB)+4)*stride)); \
  asm volatile("global_load_dwordx4 %0, %1, off nt" : "=v"(P##5) : "v"(a4 + tid + (size_t)((GB)+5)*stride)); \
  asm volatile("global_load_dwordx4 %0, %1, off nt" : "=v"(P##6) : "v"(a4 + tid + (size_t)((GB)+6)*stride)); \
  asm volatile("global_load_dwordx4 %0, %1, off nt" : "=v"(P##7) : "v"(a4 + tid + (size_t)((GB)+7)*stride)); \
}while(0)
#define PROC1(XX, GI) do{ \
  _Pragma("unroll") \
  for (int e=0;e<4;e++){ \
    if (XX[e] > ETH){ \
      size_t li = (tid + (size_t)(GI)*stride)*4 + e; \
      u32 i = (u32)(li >> 14), j = (u32)(li & 16383); \
      u32 key = (i<<14)|j; \
      bool keep = true; \
      if ((rowmod[i>>5]>>(i&31))&1u){ \
        for (int c=0;c<nm;c++) if (modkeys[c]==key){ keep=false; break; } \
      } \
      if (keep){ \
        u64 wv = vseed[i]; \
        if (wv) atomicOr(&vout[j], wv); \
        int p = atomicAdd(&lcnt, 1); \
        if (p < LCAP) lbuf[p] = key; \
        else { int d = atomicAdd(ecnt,1); if (d < EDGE_CAP) edges[d] = key; } \
      } \
    } \
  } }while(0)
#define PROC8(P, GB) do{ \
  PROC1(P##0,(GB)+0); PROC1(P##1,(GB)+1); PROC1(P##2,(GB)+2); PROC1(P##3,(GB)+3); \
  PROC1(P##4,(GB)+4); PROC1(P##5,(GB)+5); PROC1(P##6,(GB)+6); PROC1(P##7,(GB)+7); \
}while(0)

__global__ __launch_bounds__(256) void scan_adj_k(const float* __restrict__ adj,
    const u32* __restrict__ rowmod, const u32* __restrict__ modkeys,
    const int* __restrict__ ctrl, u32* __restrict__ edges, int* __restrict__ ecnt,
    const u64* __restrict__ vseed, u64* __restrict__ vout){
  __shared__ u32 lbuf[LCAP];
  __shared__ int lcnt, gbase;
  int t = threadIdx.x;
  if (t==0) lcnt = 0;
  __syncthreads();
  int nm = ctrl[1];
  size_t tid = (size_t)blockIdx.x*256 + t;
  size_t stride = (size_t)gridDim.x*256;
  const f32x4* a4 = (const f32x4*)adj;
  const size_t total4 = (size_t)NN*NN/4;
  const int iters = (int)(total4 / stride);      // 128; 128 % 16 == 0
  f32x4 xa0,xa1,xa2,xa3,xa4,xa5,xa6,xa7;
  f32x4 xb0,xb1,xb2,xb3,xb4,xb5,xb6,xb7;
  ISSUE(xa, 0);
  #pragma unroll 1
  for (int g=0; g<iters; g+=2*GITER){
    ISSUE(xb, g+GITER);
    asm volatile("s_waitcnt vmcnt(8)" ::: "memory");
    __builtin_amdgcn_sched_barrier(0);
    PROC8(xa, g);
    if (g + 2*GITER < iters){
      ISSUE(xa, g+2*GITER);
      asm volatile("s_waitcnt vmcnt(8)" ::: "memory");
    } else {
      asm volatile("s_waitcnt vmcnt(0)" ::: "memory");
    }
    __builtin_amdgcn_sched_barrier(0);
    PROC8(xb, g+GITER);
  }
  __syncthreads();
  int cnt = lcnt; if (cnt > LCAP) cnt = LCAP;
  if (cnt > 0){
    if (t==0) gbase = atomicAdd(ecnt, cnt);
    __syncthreads();
    int b0 = gbase;
    for (int i=t; i<cnt; i+=256){
      int d = b0 + i;
      if (d < EDGE_CAP) edges[d] = lbuf[i];
    }
  }
}

// ---------- append add-edges + their hop-1 contribution ----------
__global__ void patch_add_k(const u32* __restrict__ addkeys, const int* __restrict__ ctrl,
    u32* __restrict__ edges, int* __restrict__ ecnt,
    const u64* __restrict__ vseed, u64* __restrict__ vout){
  if (blockIdx.x==0 && threadIdx.x==0){
    int na = ctrl[2];
    int base = atomicAdd(ecnt, na);
    for (int i=0;i<na;i++){
      u32 key = addkeys[i];
      if (base+i < EDGE_CAP) edges[base+i] = key;
      u32 ii = key>>14, jj = key & 16383u;
      u64 wv = vseed[ii];
      if (wv) atomicOr(&vout[jj], wv);
    }
  }
}

// ---------- hop-2 over edge list ----------
__global__ __launch_bounds__(256) void propagate_k(const u32* __restrict__ edges,
    const int* __restrict__ ecnt, const u64* __restrict__ vin, u64* __restrict__ vout){
  int n = *ecnt; if (n > EDGE_CAP) n = EDGE_CAP;
  int tid = blockIdx.x*256 + threadIdx.x;
  int stride = gridDim.x*256;
  for (int idx=tid; idx<n; idx+=stride){
    u32 key = edges[idx];
    u32 i = key>>14, j = key & 16383u;
    u64 wv = vin[i];
    if (wv) atomicOr(&vout[j], wv);
  }
}

// ---------- fused q projection + Wk fold: qW[b,h,:] ----------
__global__ __launch_bounds__(256) void qprojw_k(const float* __restrict__ query,
    const float* __restrict__ w_in, const float* __restrict__ b_in, float* __restrict__ qW){
  int b = blockIdx.x, t = threadIdx.x;
  __shared__ float q_l[256], qp[256];
  q_l[t] = query[(size_t)b*256 + t];
  __syncthreads();
  float s = b_in[t];
  const float* wr = w_in + (size_t)t*256;
  for (int c=0;c<256;c++) s += q_l[c]*wr[c];
  qp[t] = s;
  __syncthreads();
  #pragma unroll
  for (int h=0; h<4; h++){
    float acc = 0.f;
    for (int dh=0; dh<64; dh++)
      acc += qp[h*64+dh] * w_in[(size_t)(256 + h*64 + dh)*256 + t];
    qW[(size_t)(b*4+h)*256 + t] = acc;
  }
}

// ---------- flash-style agg: per-chunk (m, sum, unnormalized pvec) ----------
__global__ __launch_bounds__(256) void agg_k(const float* __restrict__ scores,
    const u64* __restrict__ vis, const float* __restrict__ nodes,
    float* __restrict__ partial, float* __restrict__ m_arr, float* __restrict__ s_arr){
  int c = blockIdx.x;
  int h = blockIdx.y;
  int t = threadIdx.x;
  int bb = t >> 2, qq = t & 3;
  __shared__ float att[64][257];
  int n0 = c*256;
  for (int idx=t; idx<64*256; idx+=256){
    int rb = idx>>8, nn = idx&255;
    int node = n0 + nn;
    float raw = scores[((size_t)(rb*4+h))*NN + node];
    att[rb][nn] = ((vis[node]>>rb)&1ull) ? raw : -3.0e38f;
  }
  __syncthreads();
  float m = -3.0e38f;
  for (int j=0;j<64;j++) m = fmaxf(m, att[bb][qq*64+j]);
  m = fmaxf(m, __shfl_xor(m,1));
  m = fmaxf(m, __shfl_xor(m,2));
  float s = 0.f;
  for (int j=0;j<64;j++){ float v = att[bb][qq*64+j]; if (v > -1.0e37f) s += __expf(v-m); }
  s += __shfl_xor(s,1);
  s += __shfl_xor(s,2);
  __syncthreads();
  for (int j=0;j<64;j++){
    float v = att[bb][qq*64+j];
    att[bb][qq*64+j] = (v > -1.0e37f) ? __expf(v-m) : 0.f;
  }
  __syncthreads();
  float4 acc[16];
  #pragma unroll
  for (int i=0;i<16;i++) acc[i] = make_float4(0.f,0.f,0.f,0.f);
  for (int nn=0; nn<256; nn++){
    float a = att[bb][nn];
    if (a != 0.f){
      const float4* nr = (const float4*)(nodes + ((size_t)(n0+nn))*DD + qq*64);
      #pragma unroll
      for (int i=0;i<16;i++){
        float4 x = nr[i];
        acc[i].x += a*x.x; acc[i].y += a*x.y; acc[i].z += a*x.z; acc[i].w += a*x.w;
      }
    }
  }
  float* dst = partial + (((size_t)(c*4+h)*64 + bb)*256) + qq*64;
  #pragma unroll
  for (int i=0;i<16;i++) ((float4*)dst)[i] = acc[i];
  if (qq==0){
    m_arr[(c*4+h)*64 + bb] = m;
    s_arr[(c*4+h)*64 + bb] = s;
  }
}

// ---------- fused tail: flash recombine -> ctx -> attended -> GRU ----------
__global__ __launch_bounds__(256) void tail_k(const float* __restrict__ partial,
    const float* __restrict__ m_arr, const float* __restrict__ s_arr,
    const float* __restrict__ w_in, const float* __restrict__ b_in,
    const float* __restrict__ w_out, const float* __restrict__ b_out,
    const float* __restrict__ query,
    const float* __restrict__ w_ih, const float* __restrict__ w_hh,
    const float* __restrict__ b_ih, const float* __restrict__ b_hh,
    float* __restrict__ out){
  int b = blockIdx.x, t = threadIdx.x;
  __shared__ float lm[256], ls[256];          // (c*4+h) -> m, s for this b
  __shared__ float cr[4][256];                // ctxraw per head
  __shared__ float cx[256], at[256];
  lm[t] = m_arr[t*64 + b];
  ls[t] = s_arr[t*64 + b];
  __syncthreads();
  // stage 1: online flash recombine over 64 chunks, per (h, d=t)
  #pragma unroll
  for (int h=0; h<4; h++){
    float M = -3.0e38f, S = 0.f, acc = 0.f;
    for (int c=0; c<64; c++){
      float mc = lm[c*4+h], sc = ls[c*4+h];
      float pv = partial[((size_t)((c*4+h)*64 + b))*256 + t];
      if (mc > M){
        float w = __expf(M - mc);
        acc = acc*w + pv;
        S   = S*w + sc;
        M   = mc;
      } else {
        float w = __expf(mc - M);
        acc += pv*w;
        S   += sc*w;
      }
    }
    cr[h][t] = acc / S;
  }
  __syncthreads();
  // stage 2: ctx = Wv @ ctxraw + bv
  {
    int hh = t >> 6;
    const float* wr = w_in + (size_t)(512+t)*256;
    float s = b_in[512+t];
    for (int d=0; d<256; d++) s += cr[hh][d]*wr[d];
    cx[t] = s;
  }
  __syncthreads();
  // stage 3: attended = W_out @ ctx + b_out
  {
    const float* wr = w_out + (size_t)t*256;
    float s = b_out[t];
    for (int c=0;c<256;c++) s += cx[c]*wr[c];
    at[t] = s;
  }
  __syncthreads();
  // stage 4: GRU
  {
    const float* q = query + (size_t)b*256;
    float ir=b_ih[t], iz=b_ih[256+t], inn=b_ih[512+t];
    float hr=b_hh[t], hz=b_hh[256+t], hn=b_hh[512+t];
    for (int c=0;c<256;c++){
      float qc=q[c], ac=at[c];
      ir += qc*w_ih[(size_t)t*256+c];
      iz += qc*w_ih[(size_t)(256+t)*256+c];
      inn+= qc*w_ih[(size_t)(512+t)*256+c];
      hr += ac*w_hh[(size_t)t*256+c];
      hz += ac*w_hh[(size_t)(256+t)*256+c];
      hn += ac*w_hh[(size_t)(512+t)*256+c];
    }
    float r = 1.f/(1.f+expf(-(ir+hr)));
    float z = 1.f/(1.f+expf(-(iz+hz)));
    float nval = tanhf(inn + r*hn);
    out[(size_t)b*256+t] = (1.f-z)*nval + z*at[t];
  }
}

extern "C" void kernel_launch(void* const* d_in, const int* in_sizes, int n_in,
                              void* d_out, int out_size, void* d_ws, size_t ws_size,
                              hipStream_t stream){
  (void)in_sizes; (void)n_in; (void)out_size; (void)ws_size;
  const float* nodes     = (const float*)d_in[0];
  const float* node_vals = (const float*)d_in[1];
  const float* adjacency = (const float*)d_in[2];
  const float* related   = (const float*)d_in[3];
  const float* query     = (const float*)d_in[4];
  const float* w_in      = (const float*)d_in[5];
  const float* b_in      = (const float*)d_in[6];
  const float* w_out     = (const float*)d_in[7];
  const float* b_out     = (const float*)d_in[8];
  const float* rel_w1    = (const float*)d_in[9];
  const float* rel_b1    = (const float*)d_in[10];
  const float* rel_w2    = (const float*)d_in[11];
  const float* rel_b2    = (const float*)d_in[12];
  const float* rel_w3    = (const float*)d_in[13];
  const float* rel_b3    = (const float*)d_in[14];
  const float* gw_ih     = (const float*)d_in[15];
  const float* gw_hh     = (const float*)d_in[16];
  const float* gb_ih     = (const float*)d_in[17];
  const float* gb_hh     = (const float*)d_in[18];
  const int*   ts        = (const int*)d_in[19];
  const int*   write_idx = (const int*)d_in[20];
  const int*   tw        = (const int*)d_in[21];
  float* out = (float*)d_out;

  char* ws = (char*)d_ws;
  size_t off = 0;
  auto alloc = [&](size_t bytes)->char*{
    char* p = ws + off; off += (bytes + 255) & ~(size_t)255; return p;
  };
  float* inv_norm = (float*)alloc(NN*4);
  float* sal      = (float*)alloc(NN*4);
  float* qr       = (float*)alloc(128*DD*4);
  float* simw     = (float*)alloc((size_t)64*NN*4);
  float* wsims    = (float*)alloc((size_t)64*NN*4);
  int*   nbr      = (int*)  alloc(64*3*4);
  int*   seed     = (int*)  alloc(64*5*4);
  float* qW       = (float*)alloc(256*256*4);
  float* scores   = (float*)alloc((size_t)256*NN*4);
  float* m_arr    = (float*)alloc(64*4*64*4);
  float* s_arr    = (float*)alloc(64*4*64*4);
  u64*   V0       = (u64*)  alloc(NN*8);
  u64*   V1       = (u64*)  alloc(NN*8);
  u32*   edges    = (u32*)  alloc((size_t)EDGE_CAP*4);
  float* partial  = (float*)edges;  // alias: edges dead before agg stage
  int*   ctrl     = (int*)  alloc(256);          // [0]=ecnt [1]=nmod [2]=nadd
  u32*   modkeys  = (u32*)  alloc(512*4);
  u32*   addkeys  = (u32*)  alloc(512*4);
  u32*   rowmod   = (u32*)  alloc(NN/8);

  // zero the control/bitmap/visited state (fresh every call)
  hipMemsetAsync(ctrl, 0, 256, stream);
  hipMemsetAsync(rowmod, 0, NN/8, stream);
  hipMemsetAsync(V0, 0, NN*8, stream);

  node_stats_k<<<NN/4, 256, 0, stream>>>(nodes, node_vals, ts, tw, inv_norm, sal);
  norm_qr_k<<<128, 64, 0, stream>>>(query, related, qr);
  gemm_smallM_k<4><<<NN/64, 256, 0, stream>>>(qr, nodes, simw, wsims, inv_norm, sal, 0);
  topk_k<<<64, 1024, 0, stream>>>(simw, 3, nbr, (u64*)nullptr);
  topk_k<<<64, 1024, 0, stream>>>(wsims, 5, seed, V0);
  rel_patch_k<<<64, 256, 0, stream>>>(nodes, write_idx, nbr, rel_w1, rel_b1, rel_w2, rel_b2,
                                      rel_w3, rel_b3, modkeys, addkeys, ctrl, rowmod);
  // V1 starts as seed set; scan fuses hop-1 (V1 |= V0[i] per surviving edge)
  hipMemcpyAsync(V1, V0, NN*8, hipMemcpyDeviceToDevice, stream);
  scan_adj_k<<<2048, 256, 0, stream>>>(adjacency, rowmod, modkeys, ctrl, edges, &ctrl[0], V0, V1);
  patch_add_k<<<1, 64, 0, stream>>>(addkeys, ctrl, edges, &ctrl[0], V0, V1);
  // hop 2: V0 = V1 | prop(V1)
  hipMemcpyAsync(V0, V1, NN*8, hipMemcpyDeviceToDevice, stream);
  propagate_k<<<1024, 256, 0, stream>>>(edges, &ctrl[0], V1, V0);
  // attention (K folded into q; softmax fused flash-style; V folded post-agg)
  qprojw_k<<<64, 256, 0, stream>>>(query, w_in, b_in, qW);
  gemm_smallM_k<8><<<NN/64, 256, 0, stream>>>(qW, nodes, scores, (float*)nullptr,
                                              (const float*)nullptr, (const float*)nullptr, 1);
  agg_k<<<dim3(64,4), 256, 0, stream>>>(scores, V0, nodes, partial, m_arr, s_arr);
  tail_k<<<64, 256, 0, stream>>>(partial, m_arr, s_arr, w_in, b_in, w_out, b_out,
                                 query, gw_ih, gw_hh, gb_ih, gb_hh, out);
}

// Round 13
// 1260.268 us; speedup vs baseline: 1.0659x; 1.0659x over previous
//
#include <hip/hip_runtime.h>
#include <math.h>
#include <stdint.h>

#define NN 16384
#define DD 256
#define ETH 0.3f
#define EDGE_CAP (4*1024*1024)

typedef unsigned long long u64;
typedef uint32_t u32;
typedef float f32x4 __attribute__((ext_vector_type(4)));

// ---------- per-node stats: inverse L2 norm, salience = sigmoid(nv)*recency ----------
__global__ __launch_bounds__(256) void node_stats_k(const float* __restrict__ nodes,
    const float* __restrict__ nv, const int* __restrict__ ts, const int* __restrict__ tw,
    float* __restrict__ inv_norm, float* __restrict__ sal){
  int row = blockIdx.x*4 + (threadIdx.x>>6);
  int lane = threadIdx.x & 63;
  const float4* r4 = (const float4*)(nodes + (size_t)row*DD);
  float4 v = r4[lane];
  float s = v.x*v.x+v.y*v.y+v.z*v.z+v.w*v.w;
  #pragma unroll
  for (int o=32;o>0;o>>=1) s += __shfl_down(s,o);
  if (lane==0){
    inv_norm[row] = 1.0f/(sqrtf(s)+1e-8f);
    float x = nv[row];
    float sig = 1.0f/(1.0f+expf(-x));
    float rec = expf(-0.01f*(float)(tw[0]-ts[row]));
    sal[row] = sig*rec;
  }
}

// ---------- normalize related_pos (rows 0..63) and query (rows 64..127) into qr ----------
__global__ __launch_bounds__(64) void norm_qr_k(const float* __restrict__ query,
    const float* __restrict__ related, float* __restrict__ qr){
  int blk = blockIdx.x; int lane = threadIdx.x;
  const float* src = (blk<64)? (related + (size_t)blk*DD) : (query + (size_t)(blk-64)*DD);
  float4 v = ((const float4*)src)[lane];
  float s = v.x*v.x+v.y*v.y+v.z*v.z+v.w*v.w;
  #pragma unroll
  for (int o=32;o>0;o>>=1) s += __shfl_down(s,o);
  s = __shfl(s,0);
  float inv = 1.0f/(sqrtf(s)+1e-8f);
  ((float4*)(qr + (size_t)blk*DD))[lane] = make_float4(v.x*inv,v.y*inv,v.z*inv,v.w*inv);
}

// ---------- small-M GEMM vs nodes^T.  mode0: Qm=[rn;qn] (M=128) -> simw,wsims.
// mode1: Qm=qW (M=256) -> scores*0.125 ----------
#define ACC8(r) do{ \
    accA[r].x += qs*nv0.x; accA[r].y += qs*nv0.y; accA[r].z += qs*nv0.z; accA[r].w += qs*nv0.w; \
    accB[r].x += qs*nv1.x; accB[r].y += qs*nv1.y; accB[r].z += qs*nv1.z; accB[r].w += qs*nv1.w; }while(0)

template<int RM>
__global__ __launch_bounds__(256) void gemm_smallM_k(const float* __restrict__ Qm,
    const float* __restrict__ nodes, float* __restrict__ out0, float* __restrict__ out1,
    const float* __restrict__ inv_norm, const float* __restrict__ sal, int mode){
  constexpr int M = RM*32;
  constexpr int KC = 32;
  __shared__ float qk[KC*M];
  __shared__ float ndk[KC*64];
  int t = threadIdx.x;
  int qg = t>>3, ng = t&7;
  int n0 = blockIdx.x*64;
  float4 accA[RM], accB[RM];
  #pragma unroll
  for (int r=0;r<RM;r++){ accA[r]=make_float4(0,0,0,0); accB[r]=make_float4(0,0,0,0); }
  for (int kb=0; kb<DD; kb+=KC){
    if (t < M){
      const float4* src = (const float4*)(Qm + (size_t)t*DD + kb);
      #pragma unroll
      for (int i=0;i<KC/4;i++){
        float4 w = src[i];
        qk[(i*4+0)*M+t]=w.x; qk[(i*4+1)*M+t]=w.y;
        qk[(i*4+2)*M+t]=w.z; qk[(i*4+3)*M+t]=w.w;
      }
    }
    {
      int nn = t&63, kq = t>>6;
      const float4* src = (const float4*)(nodes + (size_t)(n0+nn)*DD + kb + kq*8);
      float4 a = src[0], b = src[1];
      ndk[(kq*8+0)*64+nn]=a.x; ndk[(kq*8+1)*64+nn]=a.y; ndk[(kq*8+2)*64+nn]=a.z; ndk[(kq*8+3)*64+nn]=a.w;
      ndk[(kq*8+4)*64+nn]=b.x; ndk[(kq*8+5)*64+nn]=b.y; ndk[(kq*8+6)*64+nn]=b.z; ndk[(kq*8+7)*64+nn]=b.w;
    }
    __syncthreads();
    for (int k=0;k<KC;k++){
      float4 nv0 = *(const float4*)&ndk[k*64 + ng*8];
      float4 nv1 = *(const float4*)&ndk[k*64 + ng*8 + 4];
      float4 q0  = *(const float4*)&qk[k*M + qg*RM];
      float qs;
      qs=q0.x; ACC8(0); qs=q0.y; ACC8(1); qs=q0.z; ACC8(2); qs=q0.w; ACC8(3);
      if constexpr (RM==8){
        float4 q1 = *(const float4*)&qk[k*M + qg*RM + 4];
        qs=q1.x; ACC8(4); qs=q1.y; ACC8(5); qs=q1.z; ACC8(6); qs=q1.w; ACC8(7);
      }
    }
    __syncthreads();
  }
  int nbase = n0 + ng*8;
  float4 in0, in1, sa0, sa1;
  if (mode==0){
    in0 = *(const float4*)&inv_norm[nbase]; in1 = *(const float4*)&inv_norm[nbase+4];
    sa0 = *(const float4*)&sal[nbase];      sa1 = *(const float4*)&sal[nbase+4];
  }
  #pragma unroll
  for (int r=0;r<RM;r++){
    int row = qg*RM + r;
    float4 a = accA[r], b = accB[r];
    if (mode==0){
      float4 s0 = make_float4(a.x*in0.x, a.y*in0.y, a.z*in0.z, a.w*in0.w);
      float4 s1 = make_float4(b.x*in1.x, b.y*in1.y, b.z*in1.z, b.w*in1.w);
      if (row < 64){
        *(float4*)&out0[(size_t)row*NN + nbase]     = s0;
        *(float4*)&out0[(size_t)row*NN + nbase + 4] = s1;
      } else {
        float4 w0 = make_float4(s0.x*sa0.x, s0.y*sa0.y, s0.z*sa0.z, s0.w*sa0.w);
        float4 w1 = make_float4(s1.x*sa1.x, s1.y*sa1.y, s1.z*sa1.z, s1.w*sa1.w);
        *(float4*)&out1[(size_t)(row-64)*NN + nbase]     = w0;
        *(float4*)&out1[(size_t)(row-64)*NN + nbase + 4] = w1;
      }
    } else {
      float4 s0 = make_float4(a.x*0.125f, a.y*0.125f, a.z*0.125f, a.w*0.125f);
      float4 s1 = make_float4(b.x*0.125f, b.y*0.125f, b.z*0.125f, b.w*0.125f);
      *(float4*)&out0[(size_t)row*NN + nbase]     = s0;
      *(float4*)&out0[(size_t)row*NN + nbase + 4] = s1;
    }
  }
}

// ---------- single-pass top-K: register top-5 + LDS tree merge (JAX tie-break) ----------
#define TK_INS(cv,ci) do{ \
  if (cv>v4 || (cv==v4 && ci<i4)){ \
    if (cv>v0 || (cv==v0 && ci<i0)){ v4=v3;i4=i3; v3=v2;i3=i2; v2=v1;i2=i1; v1=v0;i1=i0; v0=cv;i0=ci; } \
    else if (cv>v1 || (cv==v1 && ci<i1)){ v4=v3;i4=i3; v3=v2;i3=i2; v2=v1;i2=i1; v1=cv;i1=ci; } \
    else if (cv>v2 || (cv==v2 && ci<i2)){ v4=v3;i4=i3; v3=v2;i3=i2; v2=cv;i2=ci; } \
    else if (cv>v3 || (cv==v3 && ci<i3)){ v4=v3;i4=i3; v3=cv;i3=ci; } \
    else { v4=cv;i4=ci; } \
  } \
}while(0)

__global__ __launch_bounds__(1024) void topk_k(const float* __restrict__ src, int K,
    int* __restrict__ outIdx, u64* __restrict__ vis){
  int b = blockIdx.x, t = threadIdx.x;
  const float* row = src + (size_t)b*NN;
  float v0=-3.0e38f,v1=-3.0e38f,v2=-3.0e38f,v3=-3.0e38f,v4=-3.0e38f;
  int i0=0x7fffffff,i1=0x7fffffff,i2=0x7fffffff,i3=0x7fffffff,i4=0x7fffffff;
  for (int n=t; n<NN; n+=1024){
    float cv = row[n];
    TK_INS(cv, n);
  }
  __shared__ float sv[1024*5];
  __shared__ int   si[1024*5];
  sv[t*5+0]=v0; si[t*5+0]=i0; sv[t*5+1]=v1; si[t*5+1]=i1;
  sv[t*5+2]=v2; si[t*5+2]=i2; sv[t*5+3]=v3; si[t*5+3]=i3;
  sv[t*5+4]=v4; si[t*5+4]=i4;
  __syncthreads();
  for (int s=512; s>0; s>>=1){
    if (t < s){
      #pragma unroll
      for (int k=0;k<5;k++){
        float cv = sv[(t+s)*5+k]; int ci = si[(t+s)*5+k];
        TK_INS(cv, ci);
      }
      sv[t*5+0]=v0; si[t*5+0]=i0; sv[t*5+1]=v1; si[t*5+1]=i1;
      sv[t*5+2]=v2; si[t*5+2]=i2; sv[t*5+3]=v3; si[t*5+3]=i3;
      sv[t*5+4]=v4; si[t*5+4]=i4;
    }
    __syncthreads();
  }
  if (t==0){
    int idxs[5] = {i0,i1,i2,i3,i4};
    for (int kk=0; kk<K; kk++){
      outIdx[b*K+kk] = idxs[kk];
      if (vis) atomicOr(&vis[idxs[kk]], 1ull<<b);
    }
  }
}

// ---------- relation MLP -> edge patches (mod/add key lists + row bitmap) ----------
__global__ __launch_bounds__(256) void rel_patch_k(const float* __restrict__ nodes,
    const int* __restrict__ write_idx, const int* __restrict__ nbr,
    const float* __restrict__ w1, const float* __restrict__ b1,
    const float* __restrict__ w2, const float* __restrict__ b2,
    const float* __restrict__ w3, const float* __restrict__ b3,
    u32* __restrict__ modkeys, u32* __restrict__ addkeys, int* __restrict__ ctrl,
    u32* __restrict__ rowmod){
  int b = blockIdx.x, t = threadIdx.x;
  __shared__ float comb[512], h1[256], red[128];
  int w = write_idx[b];
  for (int k=0;k<3;k++){
    int nb = nbr[b*3+k];
    comb[t]     = nodes[(size_t)w*DD + t];
    comb[256+t] = nodes[(size_t)nb*DD + t];
    __syncthreads();
    float a1 = b1[t];
    for (int i=0;i<512;i++) a1 += comb[i]*w1[(size_t)i*256 + t];
    h1[t] = a1>0.f ? a1 : 0.f;
    __syncthreads();
    if (t<128){
      float a2 = b2[t];
      for (int i=0;i<256;i++) a2 += h1[i]*w2[(size_t)i*128 + t];
      float h2 = a2>0.f ? a2 : 0.f;
      red[t] = h2*w3[t];
    }
    __syncthreads();
    for (int s=64;s>0;s>>=1){ if (t<s) red[t]+=red[t+s]; __syncthreads(); }
    if (t==0 && nb != w){
      float strength = 1.0f/(1.0f+expf(-(red[0]+b3[0])));
      u32 k1 = ((u32)w<<14)|(u32)nb, k2 = ((u32)nb<<14)|(u32)w;
      int m = atomicAdd(&ctrl[1],2);
      modkeys[m]=k1; modkeys[m+1]=k2;
      if (strength > ETH){ int a=atomicAdd(&ctrl[2],2); addkeys[a]=k1; addkeys[a+1]=k2; }
      atomicOr(&rowmod[(u32)w>>5], 1u<<((u32)w&31));
      atomicOr(&rowmod[(u32)nb>>5], 1u<<((u32)nb&31));
    }
    __syncthreads();
  }
}

// ---------- 1 GB adjacency scan -> packed edge list (r9 structure: known best). ----------
#define LCAP 4096
#define GITER 8
#define ISSUE(P, GB) do{ \
  asm volatile("global_load_dwordx4 %0, %1, off" : "=v"(P##0) : "v"(a4 + tid + (size_t)((GB)+0)*stride)); \
  asm volatile("global_load_dwordx4 %0, %1, off" : "=v"(P##1) : "v"(a4 + tid + (size_t)((GB)+1)*stride)); \
  asm volatile("global_load_dwordx4 %0, %1, off" : "=v"(P##2) : "v"(a4 + tid + (size_t)((GB)+2)*stride)); \
  asm volatile("global_load_dwordx4 %0, %1, off" : "=v"(P##3) : "v"(a4 + tid + (size_t)((GB)+3)*stride)); \
  asm volatile("global_load_dwordx4 %0, %1, off" : "=v"(P##4) : "v"(a4 + tid + (size_t)((GB)+4)*stride)); \
  asm volatile("global_load_dwordx4 %0, %1, off" : "=v"(P##5) : "v"(a4 + tid + (size_t)((GB)+5)*stride)); \
  asm volatile("global_load_dwordx4 %0, %1, off" : "=v"(P##6) : "v"(a4 + tid + (size_t)((GB)+6)*stride)); \
  asm volatile("global_load_dwordx4 %0, %1, off" : "=v"(P##7) : "v"(a4 + tid + (size_t)((GB)+7)*stride)); \
}while(0)
#define PROC1(XX, GI) do{ \
  _Pragma("unroll") \
  for (int e=0;e<4;e++){ \
    if (XX[e] > ETH){ \
      size_t li = (tid + (size_t)(GI)*stride)*4 + e; \
      u32 i = (u32)(li >> 14), j = (u32)(li & 16383); \
      u32 key = (i<<14)|j; \
      bool keep = true; \
      if ((rowmod[i>>5]>>(i&31))&1u){ \
        for (int c=0;c<nm;c++) if (modkeys[c]==key){ keep=false; break; } \
      } \
      if (keep){ \
        int p = atomicAdd(&lcnt, 1); \
        if (p < LCAP) lbuf[p] = key; \
        else { int d = atomicAdd(ecnt,1); if (d < EDGE_CAP) edges[d] = key; } \
      } \
    } \
  } }while(0)
#define PROC8(P, GB) do{ \
  PROC1(P##0,(GB)+0); PROC1(P##1,(GB)+1); PROC1(P##2,(GB)+2); PROC1(P##3,(GB)+3); \
  PROC1(P##4,(GB)+4); PROC1(P##5,(GB)+5); PROC1(P##6,(GB)+6); PROC1(P##7,(GB)+7); \
}while(0)

__global__ __launch_bounds__(256) void scan_adj_k(const float* __restrict__ adj,
    const u32* __restrict__ rowmod, const u32* __restrict__ modkeys,
    const int* __restrict__ ctrl, u32* __restrict__ edges, int* __restrict__ ecnt){
  __shared__ u32 lbuf[LCAP];
  __shared__ int lcnt, gbase;
  int t = threadIdx.x;
  if (t==0) lcnt = 0;
  __syncthreads();
  int nm = ctrl[1];
  size_t tid = (size_t)blockIdx.x*256 + t;
  size_t stride = (size_t)gridDim.x*256;
  const f32x4* a4 = (const f32x4*)adj;
  const size_t total4 = (size_t)NN*NN/4;
  const int iters = (int)(total4 / stride);      // 128 with grid 2048x256; 128 % 16 == 0
  f32x4 xa0,xa1,xa2,xa3,xa4,xa5,xa6,xa7;
  f32x4 xb0,xb1,xb2,xb3,xb4,xb5,xb6,xb7;
  ISSUE(xa, 0);
  #pragma unroll 1
  for (int g=0; g<iters; g+=2*GITER){
    ISSUE(xb, g+GITER);
    asm volatile("s_waitcnt vmcnt(8)" ::: "memory");
    __builtin_amdgcn_sched_barrier(0);
    PROC8(xa, g);
    if (g + 2*GITER < iters){
      ISSUE(xa, g+2*GITER);
      asm volatile("s_waitcnt vmcnt(8)" ::: "memory");
    } else {
      asm volatile("s_waitcnt vmcnt(0)" ::: "memory");
    }
    __builtin_amdgcn_sched_barrier(0);
    PROC8(xb, g+GITER);
  }
  __syncthreads();
  int cnt = lcnt; if (cnt > LCAP) cnt = LCAP;
  if (cnt > 0){
    if (t==0) gbase = atomicAdd(ecnt, cnt);
    __syncthreads();
    int b0 = gbase;
    for (int i=t; i<cnt; i+=256){
      int d = b0 + i;
      if (d < EDGE_CAP) edges[d] = lbuf[i];
    }
  }
}

__global__ void patch_add_k(const u32* __restrict__ addkeys, const int* __restrict__ ctrl,
    u32* __restrict__ edges, int* __restrict__ ecnt){
  if (blockIdx.x==0 && threadIdx.x==0){
    int na = ctrl[2];
    int base = atomicAdd(ecnt, na);
    for (int i=0;i<na;i++) if (base+i < EDGE_CAP) edges[base+i] = addkeys[i];
  }
}

// ---------- one BFS hop over edge list; visited packed as uint64 over batch ----------
__global__ __launch_bounds__(256) void propagate_k(const u32* __restrict__ edges,
    const int* __restrict__ ecnt, const u64* __restrict__ vin, u64* __restrict__ vout){
  int n = *ecnt; if (n > EDGE_CAP) n = EDGE_CAP;
  int tid = blockIdx.x*256 + threadIdx.x;
  int stride = gridDim.x*256;
  for (int idx=tid; idx<n; idx+=stride){
    u32 key = edges[idx];
    u32 i = key>>14, j = key & 16383u;
    u64 wv = vin[i];
    if (wv) atomicOr(&vout[j], wv);
  }
}

// ---------- q projection (with bias) ----------
__global__ __launch_bounds__(256) void qproj_k(const float* __restrict__ query,
    const float* __restrict__ w_in, const float* __restrict__ b_in, float* __restrict__ qproj){
  int b = blockIdx.x, o = threadIdx.x;
  float s = b_in[o];
  const float* wr = w_in + (size_t)o*256;
  const float* q = query + (size_t)b*256;
  for (int c=0;c<256;c++) s += q[c]*wr[c];
  qproj[b*256+o]=s;
}

// ---------- fold Wk into q ----------
__global__ __launch_bounds__(256) void qw_k(const float* __restrict__ qproj,
    const float* __restrict__ w_in, float* __restrict__ qW){
  int r = blockIdx.x;   // b*4+h
  int c = threadIdx.x;
  int b = r>>2, hh = r&3;
  float s=0.f;
  for (int dh=0; dh<64; dh++)
    s += qproj[b*256 + hh*64 + dh] * w_in[(size_t)(256 + hh*64 + dh)*256 + c];
  qW[(size_t)r*256+c]=s;
}

// ---------- flash-style agg: per-chunk (m, sum, unnormalized pvec) ----------
__global__ __launch_bounds__(256) void agg_k(const float* __restrict__ scores,
    const u64* __restrict__ vis, const float* __restrict__ nodes,
    float* __restrict__ partial, float* __restrict__ m_arr, float* __restrict__ s_arr){
  int c = blockIdx.x;    // 64 chunks of 256 nodes
  int h = blockIdx.y;    // 4 heads
  int t = threadIdx.x;
  int bb = t >> 2, qq = t & 3;
  __shared__ float att[64][257];
  int n0 = c*256;
  for (int idx=t; idx<64*256; idx+=256){
    int rb = idx>>8, nn = idx&255;
    int node = n0 + nn;
    float raw = scores[((size_t)(rb*4+h))*NN + node];
    att[rb][nn] = ((vis[node]>>rb)&1ull) ? raw : -3.0e38f;
  }
  __syncthreads();
  // row max over this chunk (4 threads per row, shfl combine: lanes bb*4+qq aligned)
  float m = -3.0e38f;
  for (int j=0;j<64;j++) m = fmaxf(m, att[bb][qq*64+j]);
  m = fmaxf(m, __shfl_xor(m,1));
  m = fmaxf(m, __shfl_xor(m,2));
  // row sum of exp
  float s = 0.f;
  for (int j=0;j<64;j++){ float v = att[bb][qq*64+j]; if (v > -1.0e37f) s += __expf(v-m); }
  s += __shfl_xor(s,1);
  s += __shfl_xor(s,2);
  __syncthreads();
  // transform my quarter to unnormalized p
  for (int j=0;j<64;j++){
    float v = att[bb][qq*64+j];
    att[bb][qq*64+j] = (v > -1.0e37f) ? __expf(v-m) : 0.f;
  }
  __syncthreads();
  float4 acc[16];
  #pragma unroll
  for (int i=0;i<16;i++) acc[i] = make_float4(0.f,0.f,0.f,0.f);
  for (int nn=0; nn<256; nn++){
    float a = att[bb][nn];
    if (a != 0.f){
      const float4* nr = (const float4*)(nodes + ((size_t)(n0+nn))*DD + qq*64);
      #pragma unroll
      for (int i=0;i<16;i++){
        float4 x = nr[i];
        acc[i].x += a*x.x; acc[i].y += a*x.y; acc[i].z += a*x.z; acc[i].w += a*x.w;
      }
    }
  }
  float* dst = partial + (((size_t)(c*4+h)*64 + bb)*256) + qq*64;
  #pragma unroll
  for (int i=0;i<16;i++) ((float4*)dst)[i] = acc[i];
  if (qq==0){
    m_arr[(c*4+h)*64 + bb] = m;
    s_arr[(c*4+h)*64 + bb] = s;
  }
}

// ---------- online flash recombine over 64 chunks ----------
__global__ __launch_bounds__(256) void reduce_partial_k(const float* __restrict__ partial,
    const float* __restrict__ m_arr, const float* __restrict__ s_arr,
    float* __restrict__ ctxraw){
  int idx = blockIdx.x*256 + threadIdx.x;  // 65536
  int d = idx & 255; int bh = idx >> 8;
  int hh = bh & 3, b = bh >> 2;
  float M = -3.0e38f, S = 0.f, acc = 0.f;
  for (int c=0;c<64;c++){
    int rb = (c*4+hh)*64 + b;
    float mc = m_arr[rb], sc = s_arr[rb];
    float pv = partial[((size_t)rb)*256 + d];
    if (mc > M){
      float w = __expf(M - mc);  // scale existing state down (0 on first real chunk)
      acc = acc*w + pv;
      S   = S*w + sc;
      M   = mc;
    } else {
      float w = __expf(mc - M);
      acc += pv*w;
      S   += sc*w;
    }
  }
  ctxraw[idx] = acc / S;
}

// ---------- ctx = Wv @ ctxraw + bv ----------
__global__ __launch_bounds__(256) void ctx_k(const float* __restrict__ ctxraw,
    const float* __restrict__ w_in, const float* __restrict__ b_in, float* __restrict__ ctx){
  int b = blockIdx.x, o = threadIdx.x;
  int hh = o >> 6;
  const float* cr = ctxraw + (size_t)(b*4+hh)*256;
  const float* wr = w_in + (size_t)(512+o)*256;
  float s = b_in[512+o];
  for (int d=0; d<256; d++) s += cr[d]*wr[d];
  ctx[b*256+o] = s;
}

__global__ __launch_bounds__(256) void attended_k(const float* __restrict__ ctx,
    const float* __restrict__ w_out, const float* __restrict__ b_out, float* __restrict__ att){
  int b = blockIdx.x, o = threadIdx.x;
  const float* cr = ctx + (size_t)b*256;
  const float* wr = w_out + (size_t)o*256;
  float s = b_out[o];
  for (int c=0;c<256;c++) s += cr[c]*wr[c];
  att[b*256+o] = s;
}

__global__ __launch_bounds__(256) void gru_k(const float* __restrict__ query,
    const float* __restrict__ att, const float* __restrict__ w_ih, const float* __restrict__ w_hh,
    const float* __restrict__ b_ih, const float* __restrict__ b_hh, float* __restrict__ out){
  int b = blockIdx.x, o = threadIdx.x;
  const float* q = query + (size_t)b*256;
  const float* a = att + (size_t)b*256;
  float ir=b_ih[o], iz=b_ih[256+o], inn=b_ih[512+o];
  float hr=b_hh[o], hz=b_hh[256+o], hn=b_hh[512+o];
  for (int c=0;c<256;c++){
    float qc=q[c], ac=a[c];
    ir += qc*w_ih[(size_t)o*256+c];
    iz += qc*w_ih[(size_t)(256+o)*256+c];
    inn+= qc*w_ih[(size_t)(512+o)*256+c];
    hr += ac*w_hh[(size_t)o*256+c];
    hz += ac*w_hh[(size_t)(256+o)*256+c];
    hn += ac*w_hh[(size_t)(512+o)*256+c];
  }
  float r = 1.f/(1.f+expf(-(ir+hr)));
  float z = 1.f/(1.f+expf(-(iz+hz)));
  float nval = tanhf(inn + r*hn);
  out[b*256+o] = (1.f-z)*nval + z*a[o];
}

extern "C" void kernel_launch(void* const* d_in, const int* in_sizes, int n_in,
                              void* d_out, int out_size, void* d_ws, size_t ws_size,
                              hipStream_t stream){
  (void)in_sizes; (void)n_in; (void)out_size; (void)ws_size;
  const float* nodes     = (const float*)d_in[0];
  const float* node_vals = (const float*)d_in[1];
  const float* adjacency = (const float*)d_in[2];
  const float* related   = (const float*)d_in[3];
  const float* query     = (const float*)d_in[4];
  const float* w_in      = (const float*)d_in[5];
  const float* b_in      = (const float*)d_in[6];
  const float* w_out     = (const float*)d_in[7];
  const float* b_out     = (const float*)d_in[8];
  const float* rel_w1    = (const float*)d_in[9];
  const float* rel_b1    = (const float*)d_in[10];
  const float* rel_w2    = (const float*)d_in[11];
  const float* rel_b2    = (const float*)d_in[12];
  const float* rel_w3    = (const float*)d_in[13];
  const float* rel_b3    = (const float*)d_in[14];
  const float* gw_ih     = (const float*)d_in[15];
  const float* gw_hh     = (const float*)d_in[16];
  const float* gb_ih     = (const float*)d_in[17];
  const float* gb_hh     = (const float*)d_in[18];
  const int*   ts        = (const int*)d_in[19];
  const int*   write_idx = (const int*)d_in[20];
  const int*   tw        = (const int*)d_in[21];
  float* out = (float*)d_out;

  char* ws = (char*)d_ws;
  size_t off = 0;
  auto alloc = [&](size_t bytes)->char*{
    char* p = ws + off; off += (bytes + 255) & ~(size_t)255; return p;
  };
  float* inv_norm = (float*)alloc(NN*4);
  float* sal      = (float*)alloc(NN*4);
  float* qr       = (float*)alloc(128*DD*4);
  float* simw     = (float*)alloc((size_t)64*NN*4);
  float* wsims    = (float*)alloc((size_t)64*NN*4);
  int*   nbr      = (int*)  alloc(64*3*4);
  int*   seed     = (int*)  alloc(64*5*4);
  float* qproj    = (float*)alloc(64*256*4);
  float* qW       = (float*)alloc(256*256*4);
  float* scores   = (float*)alloc((size_t)256*NN*4);
  float* m_arr    = (float*)alloc(64*4*64*4);
  float* s_arr    = (float*)alloc(64*4*64*4);
  float* ctxraw   = (float*)alloc(64*4*256*4);
  float* ctx      = (float*)alloc(64*256*4);
  float* attended = (float*)alloc(64*256*4);
  u64*   V0       = (u64*)  alloc(NN*8);
  u64*   V1       = (u64*)  alloc(NN*8);
  u32*   edges    = (u32*)  alloc((size_t)EDGE_CAP*4);
  float* partial  = (float*)edges;  // alias: edges dead before agg stage (16 MB each)
  int*   ctrl     = (int*)  alloc(256);          // [0]=ecnt [1]=nmod [2]=nadd
  u32*   modkeys  = (u32*)  alloc(512*4);
  u32*   addkeys  = (u32*)  alloc(512*4);
  u32*   rowmod   = (u32*)  alloc(NN/8);

  // zero the control/bitmap/visited state (fresh every call)
  hipMemsetAsync(ctrl, 0, 256, stream);
  hipMemsetAsync(rowmod, 0, NN/8, stream);
  hipMemsetAsync(V0, 0, NN*8, stream);

  node_stats_k<<<NN/4, 256, 0, stream>>>(nodes, node_vals, ts, tw, inv_norm, sal);
  norm_qr_k<<<128, 64, 0, stream>>>(query, related, qr);
  gemm_smallM_k<4><<<NN/64, 256, 0, stream>>>(qr, nodes, simw, wsims, inv_norm, sal, 0);
  topk_k<<<64, 1024, 0, stream>>>(simw, 3, nbr, (u64*)nullptr);
  topk_k<<<64, 1024, 0, stream>>>(wsims, 5, seed, V0);
  rel_patch_k<<<64, 256, 0, stream>>>(nodes, write_idx, nbr, rel_w1, rel_b1, rel_w2, rel_b2,
                                      rel_w3, rel_b3, modkeys, addkeys, ctrl, rowmod);
  scan_adj_k<<<2048, 256, 0, stream>>>(adjacency, rowmod, modkeys, ctrl, edges, &ctrl[0]);
  patch_add_k<<<1, 64, 0, stream>>>(addkeys, ctrl, edges, &ctrl[0]);
  // hop 1: V1 = V0 | prop(V0); hop 2: V0 = V1 | prop(V1)
  hipMemcpyAsync(V1, V0, NN*8, hipMemcpyDeviceToDevice, stream);
  propagate_k<<<1024, 256, 0, stream>>>(edges, &ctrl[0], V0, V1);
  hipMemcpyAsync(V0, V1, NN*8, hipMemcpyDeviceToDevice, stream);
  propagate_k<<<1024, 256, 0, stream>>>(edges, &ctrl[0], V1, V0);
  // attention (K folded into q, V folded post-aggregation; softmax fused flash-style)
  qproj_k<<<64, 256, 0, stream>>>(query, w_in, b_in, qproj);
  qw_k<<<256, 256, 0, stream>>>(qproj, w_in, qW);
  gemm_smallM_k<8><<<NN/64, 256, 0, stream>>>(qW, nodes, scores, (float*)nullptr,
                                              (const float*)nullptr, (const float*)nullptr, 1);
  agg_k<<<dim3(64,4), 256, 0, stream>>>(scores, V0, nodes, partial, m_arr, s_arr);
  reduce_partial_k<<<256, 256, 0, stream>>>(partial, m_arr, s_arr, ctxraw);
  ctx_k<<<64, 256, 0, stream>>>(ctxraw, w_in, b_in, ctx);
  attended_k<<<64, 256, 0, stream>>>(ctx, w_out, b_out, attended);
  gru_k<<<64, 256, 0, stream>>>(query, attended, gw_ih, gw_hh, gb_ih, gb_hh, out);
}